// Round 11
// baseline (266.713 us; speedup 1.0000x reference)
//
#include <hip/hip_runtime.h>
#include <hip/hip_bf16.h>

typedef float f32x4 __attribute__((ext_vector_type(4)));
typedef __bf16 bf16x8 __attribute__((ext_vector_type(8)));
typedef __bf16 bf16x4 __attribute__((ext_vector_type(4)));
typedef unsigned short u16x8 __attribute__((ext_vector_type(8)));
typedef unsigned short u16x4 __attribute__((ext_vector_type(4)));

#define QSCALE 0.180336881f  /* 0.125 * log2(e): folds attn scale + exp2 domain into Q */

__device__ __forceinline__ unsigned short f2bf(float f) {
  union { float f; unsigned int u; } v; v.f = f;
  return (unsigned short)((v.u + 0x7FFFu + ((v.u >> 16) & 1u)) >> 16);
}

__device__ __forceinline__ f32x4 mfma16(bf16x8 a, bf16x8 b, f32x4 c) {
  return __builtin_amdgcn_mfma_f32_16x16x32_bf16(a, b, c, 0, 0, 0);
}

__device__ __forceinline__ void gload16(const unsigned short* g, unsigned short* l) {
  __builtin_amdgcn_global_load_lds(
      (const __attribute__((address_space(1))) void*)g,
      (__attribute__((address_space(3))) void*)l, 16, 0, 0);
}

// ---------------- small utility kernels ----------------

__global__ void concat_bias_k(const float* __restrict__ qb, const float* __restrict__ kb,
                              const float* __restrict__ vb, float* __restrict__ out) {
  const int i = blockIdx.x * 256 + threadIdx.x;
  if (i >= 3072) return;
  const float* s = (i < 1024) ? qb : (i < 2048 ? kb : vb);
  out[i] = s[i & 1023] * (i < 1024 ? QSCALE : 1.0f);
}

// fp32 [R,C] -> bf16 [C,R]
__global__ void tcvt_k(const float* __restrict__ in, unsigned short* __restrict__ out,
                       int R, int C) {
  __shared__ float tile[32][33];
  const int x = blockIdx.x * 32 + threadIdx.x;
  const int y0 = blockIdx.y * 32;
#pragma unroll
  for (int i = 0; i < 32; i += 8)
    tile[threadIdx.y + i][threadIdx.x] = in[(size_t)(y0 + threadIdx.y + i) * C + x];
  __syncthreads();
  const int ox = y0 + threadIdx.x;
  const int oy0 = blockIdx.x * 32;
#pragma unroll
  for (int i = 0; i < 32; i += 8)
    out[(size_t)(oy0 + threadIdx.y + i) * R + ox] = f2bf(tile[threadIdx.x][threadIdx.y + i]);
}

__global__ void cvt_k(const float* __restrict__ in, unsigned short* __restrict__ out, int n) {
  const int i = (blockIdx.x * 256 + threadIdx.x) * 4;
  if (i >= n) return;
  const f32x4 v = *(const f32x4*)(in + i);
  u16x4 o;
#pragma unroll
  for (int k = 0; k < 4; ++k) o[k] = f2bf(v[k]);
  *(u16x4*)(out + i) = o;
}

// V-transpose: QKV[b][s][2048 + h*64 + d] -> VT[(b*16+h)][d][s]  (bf16)
__global__ void vtr_k(const unsigned short* __restrict__ QKV, unsigned short* __restrict__ VT) {
  __shared__ unsigned short tile[32][33];
  const int bh = blockIdx.z, b = bh >> 4, h = bh & 15;
  const int s0 = blockIdx.x * 32, d0 = blockIdx.y * 32;
  const unsigned short* src = QKV + (size_t)b * 2048 * 3072 + 2048 + h * 64;
#pragma unroll
  for (int i = 0; i < 32; i += 8)
    tile[threadIdx.y + i][threadIdx.x] = src[(size_t)(s0 + threadIdx.y + i) * 3072 + d0 + threadIdx.x];
  __syncthreads();
  unsigned short* dst = VT + (size_t)bh * 64 * 2048;
#pragma unroll
  for (int i = 0; i < 32; i += 8)
    dst[(size_t)(d0 + threadIdx.y + i) * 2048 + s0 + threadIdx.x] = tile[threadIdx.x][threadIdx.y + i];
}

// Wqkv^T[(m*1024 + h*64 + e)*1024 + d] = sum_r U_m[d,h,r] * V_m[h,r,e]  (Q part scaled)
__global__ __launch_bounds__(256) void wqkv_pre_k(
    const float* __restrict__ qU, const float* __restrict__ qV,
    const float* __restrict__ kU, const float* __restrict__ kV,
    const float* __restrict__ vU, const float* __restrict__ vV,
    unsigned short* __restrict__ WT) {
  __shared__ float Us[64][48];
  __shared__ float Vs[48][64];
  const int m = blockIdx.y >> 4, h = blockIdx.y & 15;
  const int d0 = blockIdx.x * 64;
  const float* U = (m == 0) ? qU : (m == 1 ? kU : vU);
  const float* V = (m == 0) ? qV : (m == 1 ? kV : vV);
  const float qs = (m == 0) ? QSCALE : 1.0f;
  const int t = threadIdx.x;
  for (int idx = t; idx < 64 * 48; idx += 256) {
    const int d = idx / 48, r = idx - d * 48;
    Us[d][r] = U[(size_t)(d0 + d) * 768 + h * 48 + r];
  }
  for (int idx = t; idx < 48 * 64; idx += 256) {
    const int r = idx >> 6, e = idx & 63;
    Vs[r][e] = V[(h * 48 + r) * 64 + e];
  }
  __syncthreads();
  const int e = t & 63, dg = t >> 6;
  for (int j = 0; j < 16; ++j) {
    const int d = dg * 16 + j;
    float s = 0.f;
#pragma unroll
    for (int r = 0; r < 48; ++r) s = fmaf(Us[d][r], Vs[r][e], s);
    WT[(size_t)(m * 1024 + h * 64 + e) * 1024 + d0 + d] = f2bf(s * qs);
  }
}

// LayerNorm over D=1024, fp32 in, bf16 out. One block per row.
__global__ __launch_bounds__(256) void ln_k(
    const float* __restrict__ in, const float* __restrict__ gw,
    const float* __restrict__ bw, unsigned short* __restrict__ out) {
  const int row = blockIdx.x, t = threadIdx.x;
  const f32x4 v = *(const f32x4*)(in + (size_t)row * 1024 + t * 4);
  float s = v[0] + v[1] + v[2] + v[3];
  float ss = v[0] * v[0] + v[1] * v[1] + v[2] * v[2] + v[3] * v[3];
#pragma unroll
  for (int off = 1; off < 64; off <<= 1) {
    s += __shfl_xor(s, off);
    ss += __shfl_xor(ss, off);
  }
  __shared__ float red[8];
  if ((t & 63) == 0) { red[(t >> 6) * 2] = s; red[(t >> 6) * 2 + 1] = ss; }
  __syncthreads();
  s = red[0] + red[2] + red[4] + red[6];
  ss = red[1] + red[3] + red[5] + red[7];
  const float mean = s * (1.0f / 1024.0f);
  const float rstd = rsqrtf(ss * (1.0f / 1024.0f) - mean * mean + 1e-5f);
  const f32x4 g4 = *(const f32x4*)(gw + t * 4);
  const f32x4 b4 = *(const f32x4*)(bw + t * 4);
  u16x4 o;
#pragma unroll
  for (int i = 0; i < 4; ++i) o[i] = f2bf((v[i] - mean) * rstd * g4[i] + b4[i]);
  *(u16x4*)(out + (size_t)row * 1024 + t * 4) = o;
}

// bijective XCD chunking (m157/m204)
__device__ __forceinline__ void xcd_swz(int& bx, int& by, int nx, int ny) {
  const int nwg = nx * ny;
  if ((nwg & 7) == 0) {
    const int d = by * nx + bx;
    const int k = (d & 7) * (nwg >> 3) + (d >> 3);
    bx = k % nx;
    by = k / nx;
  }
}

// ---------------- generic bf16 MFMA GEMM ----------------
// 4-buffer global_load_lds pipeline, 3 tiles of prefetch in flight, counted
// s_waitcnt vmcnt + raw s_barrier per K-step (T3/T4). Cover = 3 iters > HBM
// latency -> steady state never stalls on loads. bf16 out via per-wave LDS
// bounce for coalesced b128 stores.
template <int BM, int BN, int EPI, int OUTBF>
__global__ __launch_bounds__(256) void gemm_k(
    const unsigned short* __restrict__ A, const unsigned short* __restrict__ Bt,
    const float* __restrict__ bias, const float* __restrict__ resid,
    void* __restrict__ Cout, int M, int N, int K) {
  constexpr int MI = BM / 32;
  constexpr int FN = BN / 32;
  constexpr int NL = (BM == 128 ? 2 : 1) + (BN == 128 ? 2 : 1);  // gloads/thread/stage
  constexpr int SM_KLOOP = 4 * (BM + BN) * 32;
  constexpr int SM_EPI = OUTBF ? 4 * (BM / 2) * 72 : 0;
  constexpr int SME = SM_KLOOP > SM_EPI ? SM_KLOOP : SM_EPI;
  __shared__ unsigned short smem[SME];
  unsigned short* As = smem;                  // [4][BM*32]
  unsigned short* Bs = smem + 4 * BM * 32;    // [4][BN*32]
  int bxi = blockIdx.x, byi = blockIdx.y;
  xcd_swz(bxi, byi, gridDim.x, gridDim.y);
  const int t = threadIdx.x;
  const int lane = t & 63, wid = t >> 6;
  const int m0 = byi * BM, n0 = bxi * BN;
  const int wm = (wid >> 1) * (BM / 2), wn = (wid & 1) * (BN / 2);
  const int fr = lane & 15, fg = (lane >> 4) * 8;

  f32x4 acc[MI][FN];
#pragma unroll
  for (int i = 0; i < MI; ++i)
#pragma unroll
    for (int j = 0; j < FN; ++j) acc[i][j] = (f32x4){0.f, 0.f, 0.f, 0.f};

  const unsigned short* Ag0 = A + (size_t)(m0 + (t >> 2)) * K + (t & 3) * 8;
  const unsigned short* Ag1 = A + (size_t)(m0 + 64 + (t >> 2)) * K + (t & 3) * 8;
  const unsigned short* Bg0 = Bt + (size_t)(n0 + (t >> 2)) * K + (t & 3) * 8;
  const unsigned short* Bg1 = Bt + (size_t)(n0 + 64 + (t >> 2)) * K + (t & 3) * 8;
  const int l0 = t * 8;

#define GEMM_STAGE(buf, ke)                                             \
  {                                                                     \
    gload16(Ag0 + (ke), &As[(buf) * BM * 32 + l0]);                     \
    if (BM == 128) gload16(Ag1 + (ke), &As[(buf) * BM * 32 + l0 + 2048]); \
    gload16(Bg0 + (ke), &Bs[(buf) * BN * 32 + l0]);                     \
    if (BN == 128) gload16(Bg1 + (ke), &Bs[(buf) * BN * 32 + l0 + 2048]); \
  }

  const int nk = K >> 5;
  GEMM_STAGE(0, 0);
  if (nk > 1) GEMM_STAGE(1, 32);
  if (nk > 2) GEMM_STAGE(2, 64);

  for (int kt = 0; kt < nk; ++kt) {
    const int cur = kt & 3;
    // retire tile kt; leave min(2, nk-1-kt) stages in flight. Wait THEN barrier
    // = collective readiness.
    if (kt + 2 < nk)
      asm volatile("s_waitcnt vmcnt(%0)" ::"n"(2 * NL) : "memory");
    else if (kt + 1 < nk)
      asm volatile("s_waitcnt vmcnt(%0)" ::"n"(NL) : "memory");
    else
      asm volatile("s_waitcnt vmcnt(0)" ::: "memory");
    __builtin_amdgcn_s_barrier();
    __builtin_amdgcn_sched_barrier(0);
    if (kt + 3 < nk) GEMM_STAGE((kt + 3) & 3, (kt + 3) * 32);  // buf freed at this barrier
    bf16x8 af[MI], bfr[FN];
#pragma unroll
    for (int i = 0; i < MI; ++i)
      af[i] = *(const bf16x8*)&As[cur * BM * 32 + (wm + i * 16 + fr) * 32 + fg];
#pragma unroll
    for (int j = 0; j < FN; ++j)
      bfr[j] = *(const bf16x8*)&Bs[cur * BN * 32 + (wn + j * 16 + fr) * 32 + fg];
#pragma unroll
    for (int i = 0; i < MI; ++i)
#pragma unroll
      for (int j = 0; j < FN; ++j) acc[i][j] = mfma16(af[i], bfr[j], acc[i][j]);
  }
#undef GEMM_STAGE

  if (OUTBF) {
    __syncthreads();  // all waves out of the K-loop before smem reuse
    unsigned short* eb = smem + wid * ((BM / 2) * 72);  // per-wave [BM/2][72] bf16
#pragma unroll
    for (int j = 0; j < FN; ++j) {
      const int colL = j * 16 + fr;                     // wave-local column
      const float bval = (EPI >= 1) ? bias[n0 + wn + colL] : 0.0f;
#pragma unroll
      for (int i = 0; i < MI; ++i) {
#pragma unroll
        for (int r = 0; r < 4; ++r) {
          const int rl = i * 16 + ((lane >> 4) << 2) + r;
          float v = acc[i][j][r] + bval;
          if (EPI == 2) {  // gelu tanh-approx: v * sigmoid(2z)
            const float z = 0.7978845608028654f * (v + 0.044715f * v * v * v);
            v = v - v / (__expf(2.0f * z) + 1.0f);
          }
          eb[rl * 72 + colL] = f2bf(v);
        }
      }
    }
    __builtin_amdgcn_s_barrier();
    constexpr int CH = (BN / 2) / 8;
    constexpr int RPI = 64 / CH;             // rows per pass
    const int c2 = lane % CH, r2b = lane / CH;
    unsigned short* Cg = (unsigned short*)Cout;
#pragma unroll
    for (int it = 0; it < (BM / 2) / RPI; ++it) {
      const int r2 = r2b + it * RPI;
      const u16x8 vv = *(const u16x8*)&eb[r2 * 72 + c2 * 8];
      *(u16x8*)&Cg[(size_t)(m0 + wm + r2) * N + n0 + wn + c2 * 8] = vv;
    }
  } else {
#pragma unroll
    for (int j = 0; j < FN; ++j) {
      const int col = n0 + wn + j * 16 + fr;
      const float bval = (EPI >= 1) ? bias[col] : 0.0f;
#pragma unroll
      for (int i = 0; i < MI; ++i) {
#pragma unroll
        for (int r = 0; r < 4; ++r) {
          const int row = m0 + wm + i * 16 + ((lane >> 4) << 2) + r;
          float v = acc[i][j][r] + bval;
          if (EPI == 3) v += resid[(size_t)row * N + col];
          ((float*)Cout)[(size_t)row * N + col] = v;
        }
      }
    }
  }
}

// ---------------- causal flash attention (R8 structure + T13 defer-max) ----------------
__global__ __launch_bounds__(512) void attn_k(
    const unsigned short* __restrict__ QKV, const unsigned short* __restrict__ VT,
    unsigned short* __restrict__ ctx) {
  __shared__ unsigned short Ks[2][64 * 64];
  __shared__ unsigned short Vs[2][64 * 64];
  __shared__ unsigned short Ps[8][16 * 64];  // per-wave P, 16B-chunk swizzled by q&7
  int bxi = blockIdx.x, byi = blockIdx.y;
  xcd_swz(bxi, byi, 16, 32);
  const int qi = ((byi >> 1) & 1) ? (15 - bxi) : bxi;
  const int bh = byi, b = bh >> 4, h = bh & 15;
  const int nt = 2 * qi + 2;
  const int q0b = qi * 128;
  const int t = threadIdx.x, lane = t & 63, w = t >> 6;
  const int g = lane >> 4, c = lane & 15;
  const int cks = c & 7;
  const size_t base = (size_t)b * 2048 * 3072;

  const int r0 = t >> 3, ch0 = t & 7;
  const int lw = r0 * 64 + ((ch0 ^ (r0 & 7)) * 8);
  const unsigned short* Kg = QKV + base + 1024 + h * 64 + (size_t)r0 * 3072 + ch0 * 8;
  const unsigned short* Vg = VT + ((size_t)bh * 64 + r0) * 2048 + ch0 * 8;

  const int kro0 = (g ^ cks) * 8, kro1 = ((4 + g) ^ cks) * 8;

  bf16x8 onef;
#pragma unroll
  for (int i = 0; i < 8; ++i) onef[i] = (__bf16)1.0f;

  const int qrow = q0b + w * 16 + c;
  const unsigned short* qp = QKV + base + (size_t)qrow * 3072 + h * 64 + g * 8;
  const bf16x8 qf0 = *(const bf16x8*)qp;
  const bf16x8 qf1 = *(const bf16x8*)(qp + 32);

  f32x4 o[4];
#pragma unroll
  for (int d = 0; d < 4; ++d) o[d] = (f32x4){0.f, 0.f, 0.f, 0.f};
  f32x4 ol = (f32x4){0.f, 0.f, 0.f, 0.f};
  float mrow = -1e30f;

  u16x8 kr, vr;
#define ATTN_LOAD(kt_)                                        \
  {                                                           \
    kr = *(const u16x8*)(Kg + (size_t)(kt_) * 64 * 3072);     \
    vr = *(const u16x8*)(Vg + (kt_) * 64);                    \
  }
#define ATTN_WRITE(buf)                                       \
  {                                                           \
    *(u16x8*)&Ks[buf][lw] = kr;                               \
    *(u16x8*)&Vs[buf][lw] = vr;                               \
  }

  ATTN_LOAD(0);
  ATTN_WRITE(0);
  if (nt > 1) ATTN_LOAD(1);
  __syncthreads();

  const int fsrc = g * 20;

  for (int j = 0; j < nt; ++j) {
    const int cur = j & 1;
    const int kbase = j * 64;
    const bool active = (kbase <= q0b + w * 16 + 15);

    if (active) {
      f32x4 s4[4];
      __builtin_amdgcn_s_setprio(1);
#pragma unroll
      for (int t16 = 0; t16 < 4; ++t16) {
        const int krow = (t16 * 16 + c) * 64;
        const bf16x8 kf0 = *(const bf16x8*)&Ks[cur][krow + kro0];
        const bf16x8 kf1 = *(const bf16x8*)&Ks[cur][krow + kro1];
        f32x4 a = (f32x4){0.f, 0.f, 0.f, 0.f};
        a = mfma16(kf0, qf0, a);
        a = mfma16(kf1, qf1, a);
        s4[t16] = a;
      }
      __builtin_amdgcn_s_setprio(0);
      if (kbase + 63 > qrow) {
#pragma unroll
        for (int t16 = 0; t16 < 4; ++t16)
#pragma unroll
          for (int r = 0; r < 4; ++r)
            if (kbase + t16 * 16 + 4 * g + r > qrow) s4[t16][r] = -1e30f;
      }
      float mx = s4[0][0];
#pragma unroll
      for (int t16 = 0; t16 < 4; ++t16)
#pragma unroll
        for (int r = 0; r < 4; ++r) mx = fmaxf(mx, s4[t16][r]);
      mx = fmaxf(mx, __shfl_xor(mx, 16));
      mx = fmaxf(mx, __shfl_xor(mx, 32));
      // T13 defer-max: only rescale when the running max grew by > 8 (exp2
      // domain); otherwise keep m_old -> P bounded by 2^8, fp32 l safe.
      if (!__all(mx <= mrow + 8.0f)) {
        const float mn = fmaxf(mrow, mx);
        const float fac = exp2f(mrow - mn);
        mrow = mn;
        float fo[4];
#pragma unroll
        for (int r = 0; r < 4; ++r) fo[r] = __shfl(fac, fsrc + r);
#pragma unroll
        for (int d = 0; d < 4; ++d)
#pragma unroll
          for (int r = 0; r < 4; ++r) o[d][r] *= fo[r];
#pragma unroll
        for (int r = 0; r < 4; ++r) ol[r] *= fo[r];
      }
#pragma unroll
      for (int t16 = 0; t16 < 4; ++t16) {
        bf16x4 pw;
#pragma unroll
        for (int r = 0; r < 4; ++r) pw[r] = (__bf16)exp2f(s4[t16][r] - mrow);
        *(bf16x4*)&Ps[w][c * 64 + (((2 * t16 + (g >> 1)) ^ cks) * 8) + (g & 1) * 4] = pw;
      }
      __builtin_amdgcn_s_setprio(1);
#pragma unroll
      for (int ks = 0; ks < 2; ++ks) {
        const int po = ((ks * 4 + g) ^ cks) * 8;
        const bf16x8 pf = *(const bf16x8*)&Ps[w][c * 64 + po];
#pragma unroll
        for (int d = 0; d < 4; ++d) {
          const bf16x8 vf = *(const bf16x8*)&Vs[cur][(d * 16 + c) * 64 + po];
          o[d] = mfma16(pf, vf, o[d]);
        }
        ol = mfma16(pf, onef, ol);
      }
      __builtin_amdgcn_s_setprio(0);
    }

    if (j + 1 < nt) {
      __syncthreads();
      ATTN_WRITE(cur ^ 1);
      if (j + 2 < nt) ATTN_LOAD(j + 2);
      __syncthreads();
    }
  }
#pragma unroll
  for (int d = 0; d < 4; ++d)
#pragma unroll
    for (int r = 0; r < 4; ++r) {
      const float v = o[d][r] / ol[r];
      ctx[(size_t)(b * 2048 + q0b + w * 16 + g * 4 + r) * 1024 + h * 64 + d * 16 + c] = f2bf(v);
    }
#undef ATTN_LOAD
#undef ATTN_WRITE
}

// ---------------- launch ----------------

extern "C" void kernel_launch(void* const* d_in, const int* in_sizes, int n_in,
                              void* d_out, int out_size, void* d_ws, size_t ws_size,
                              hipStream_t stream) {
  const float* hidden = (const float*)d_in[0];
  const float* ln1g = (const float*)d_in[1];
  const float* ln1b = (const float*)d_in[2];
  const float* ln2g = (const float*)d_in[3];
  const float* ln2b = (const float*)d_in[4];
  const float* qU = (const float*)d_in[5];
  const float* qV = (const float*)d_in[6];
  const float* qb = (const float*)d_in[7];
  const float* kU = (const float*)d_in[8];
  const float* kV = (const float*)d_in[9];
  const float* kb = (const float*)d_in[10];
  const float* vU = (const float*)d_in[11];
  const float* vV = (const float*)d_in[12];
  const float* vb = (const float*)d_in[13];
  const float* outU = (const float*)d_in[14];
  const float* outV = (const float*)d_in[15];
  const float* outb = (const float*)d_in[16];
  const float* fc1U = (const float*)d_in[17];
  const float* fc1V = (const float*)d_in[18];
  const float* fc1b = (const float*)d_in[19];
  const float* fc2U = (const float*)d_in[20];
  const float* fc2V = (const float*)d_in[21];
  const float* fc2b = (const float*)d_in[22];
  float* out = (float*)d_out;

  // workspace carve, lifetime-based aliasing
  char* p = (char*)d_ws;
  unsigned short* x1x2 = (unsigned short*)p; p += (size_t)4096 * 1024 * 2;   // x1 (LN1), later x2 (LN2)
  unsigned short* WqT_t1 = (unsigned short*)p; p += (size_t)3072 * 1024 * 2; // Wqkv^T, later t1
  float* bqkv = (float*)p; p += 3072 * 4;
  char* bigA = p; p += (size_t)4096 * 3072 * 2 + (size_t)4096 * 1024 * 2;    // QKV + ctx, later hmid
  unsigned short* QKV = (unsigned short*)bigA;
  unsigned short* ctxb = (unsigned short*)(bigA + (size_t)4096 * 3072 * 2);
  unsigned short* hmid = (unsigned short*)bigA;
  char* wo = p; p += (size_t)1024 * 768 * 2 * 2 + (size_t)1024 * 1024 * 2;   // outU,outV^T,Wout^T, later t2
  unsigned short* outUb = (unsigned short*)wo;
  unsigned short* outVT = (unsigned short*)(wo + (size_t)1024 * 768 * 2);
  unsigned short* WoutT = (unsigned short*)(wo + (size_t)1024 * 768 * 2 * 2);
  unsigned short* t2 = (unsigned short*)wo;
  float* hbuf = (float*)p; p += (size_t)4096 * 1024 * 4;                     // h (fp32 residual); VT aliases pre-attn
  unsigned short* VT = (unsigned short*)hbuf;                                // [32][64][2048] bf16 = 8MB
  unsigned short* fc1UT = (unsigned short*)p; p += (size_t)512 * 1024 * 2;
  unsigned short* fc1VT = (unsigned short*)p; p += (size_t)4096 * 512 * 2;
  unsigned short* fc2UT = (unsigned short*)p; p += (size_t)512 * 4096 * 2;
  unsigned short* fc2VT = (unsigned short*)p; p += (size_t)1024 * 512 * 2;

  const dim3 b256(256);
  const dim3 tb(32, 8);

  // weight prep
  concat_bias_k<<<12, b256, 0, stream>>>(qb, kb, vb, bqkv);
  wqkv_pre_k<<<dim3(16, 48), b256, 0, stream>>>(qU, qV, kU, kV, vU, vV, WqT_t1);
  tcvt_k<<<dim3(32, 24), tb, 0, stream>>>(outV, outVT, 768, 1024);
  cvt_k<<<768, b256, 0, stream>>>(outU, outUb, 1024 * 768);
  tcvt_k<<<dim3(16, 32), tb, 0, stream>>>(fc1U, fc1UT, 1024, 512);
  tcvt_k<<<dim3(128, 16), tb, 0, stream>>>(fc1V, fc1VT, 512, 4096);
  tcvt_k<<<dim3(16, 128), tb, 0, stream>>>(fc2U, fc2UT, 4096, 512);
  tcvt_k<<<dim3(32, 16), tb, 0, stream>>>(fc2V, fc2VT, 512, 1024);

  // attention path
  ln_k<<<4096, b256, 0, stream>>>(hidden, ln1g, ln1b, x1x2);
  gemm_k<128, 128, 1, 1><<<dim3(24, 32), b256, 0, stream>>>(x1x2, WqT_t1, bqkv, nullptr, QKV, 4096, 3072, 1024);
  vtr_k<<<dim3(64, 2, 32), tb, 0, stream>>>(QKV, VT);
  gemm_k<128, 128, 0, 1><<<dim3(8, 8), b256, 0, stream>>>(outVT, outUb, nullptr, nullptr, WoutT, 1024, 1024, 768);
  attn_k<<<dim3(16, 32), dim3(512), 0, stream>>>(QKV, VT, ctxb);
  gemm_k<64, 128, 3, 0><<<dim3(8, 64), b256, 0, stream>>>(ctxb, WoutT, outb, hidden, hbuf, 4096, 1024, 1024);

  // MLP path
  ln_k<<<4096, b256, 0, stream>>>(hbuf, ln2g, ln2b, x1x2);
  gemm_k<64, 64, 0, 1><<<dim3(8, 64), b256, 0, stream>>>(x1x2, fc1UT, nullptr, nullptr, WqT_t1, 4096, 512, 1024);
  gemm_k<128, 128, 2, 1><<<dim3(32, 32), b256, 0, stream>>>(WqT_t1, fc1VT, fc1b, nullptr, hmid, 4096, 4096, 512);
  gemm_k<64, 64, 0, 1><<<dim3(8, 64), b256, 0, stream>>>(hmid, fc2UT, nullptr, nullptr, t2, 4096, 512, 4096);
  gemm_k<64, 128, 3, 0><<<dim3(8, 64), b256, 0, stream>>>(t2, fc2VT, fc2b, hbuf, out, 4096, 1024, 512);
}

// Round 12
// 260.075 us; speedup vs baseline: 1.0255x; 1.0255x over previous
//
#include <hip/hip_runtime.h>
#include <hip/hip_bf16.h>

typedef float f32x4 __attribute__((ext_vector_type(4)));
typedef __bf16 bf16x8 __attribute__((ext_vector_type(8)));
typedef __bf16 bf16x4 __attribute__((ext_vector_type(4)));
typedef unsigned short u16x8 __attribute__((ext_vector_type(8)));
typedef unsigned short u16x4 __attribute__((ext_vector_type(4)));

#define QSCALE 0.180336881f  /* 0.125 * log2(e): folds attn scale + exp2 domain into Q */

__device__ __forceinline__ unsigned short f2bf(float f) {
  union { float f; unsigned int u; } v; v.f = f;
  return (unsigned short)((v.u + 0x7FFFu + ((v.u >> 16) & 1u)) >> 16);
}

__device__ __forceinline__ f32x4 mfma16(bf16x8 a, bf16x8 b, f32x4 c) {
  return __builtin_amdgcn_mfma_f32_16x16x32_bf16(a, b, c, 0, 0, 0);
}

__device__ __forceinline__ void gload16(const unsigned short* g, unsigned short* l) {
  __builtin_amdgcn_global_load_lds(
      (const __attribute__((address_space(1))) void*)g,
      (__attribute__((address_space(3))) void*)l, 16, 0, 0);
}

// ---------------- small utility kernels ----------------

__global__ void concat_bias_k(const float* __restrict__ qb, const float* __restrict__ kb,
                              const float* __restrict__ vb, float* __restrict__ out) {
  const int i = blockIdx.x * 256 + threadIdx.x;
  if (i >= 3072) return;
  const float* s = (i < 1024) ? qb : (i < 2048 ? kb : vb);
  out[i] = s[i & 1023] * (i < 1024 ? QSCALE : 1.0f);
}

// fp32 [R,C] -> bf16 [C,R]
__global__ void tcvt_k(const float* __restrict__ in, unsigned short* __restrict__ out,
                       int R, int C) {
  __shared__ float tile[32][33];
  const int x = blockIdx.x * 32 + threadIdx.x;
  const int y0 = blockIdx.y * 32;
#pragma unroll
  for (int i = 0; i < 32; i += 8)
    tile[threadIdx.y + i][threadIdx.x] = in[(size_t)(y0 + threadIdx.y + i) * C + x];
  __syncthreads();
  const int ox = y0 + threadIdx.x;
  const int oy0 = blockIdx.x * 32;
#pragma unroll
  for (int i = 0; i < 32; i += 8)
    out[(size_t)(oy0 + threadIdx.y + i) * R + ox] = f2bf(tile[threadIdx.x][threadIdx.y + i]);
}

__global__ void cvt_k(const float* __restrict__ in, unsigned short* __restrict__ out, int n) {
  const int i = (blockIdx.x * 256 + threadIdx.x) * 4;
  if (i >= n) return;
  const f32x4 v = *(const f32x4*)(in + i);
  u16x4 o;
#pragma unroll
  for (int k = 0; k < 4; ++k) o[k] = f2bf(v[k]);
  *(u16x4*)(out + i) = o;
}

// V-transpose: QKV[b][s][2048 + h*64 + d] -> VT[(b*16+h)][d][s]  (bf16)
__global__ void vtr_k(const unsigned short* __restrict__ QKV, unsigned short* __restrict__ VT) {
  __shared__ unsigned short tile[32][33];
  const int bh = blockIdx.z, b = bh >> 4, h = bh & 15;
  const int s0 = blockIdx.x * 32, d0 = blockIdx.y * 32;
  const unsigned short* src = QKV + (size_t)b * 2048 * 3072 + 2048 + h * 64;
#pragma unroll
  for (int i = 0; i < 32; i += 8)
    tile[threadIdx.y + i][threadIdx.x] = src[(size_t)(s0 + threadIdx.y + i) * 3072 + d0 + threadIdx.x];
  __syncthreads();
  unsigned short* dst = VT + (size_t)bh * 64 * 2048;
#pragma unroll
  for (int i = 0; i < 32; i += 8)
    dst[(size_t)(d0 + threadIdx.y + i) * 2048 + s0 + threadIdx.x] = tile[threadIdx.x][threadIdx.y + i];
}

// Wqkv^T[(m*1024 + h*64 + e)*1024 + d] = sum_r U_m[d,h,r] * V_m[h,r,e]  (Q part scaled)
__global__ __launch_bounds__(256) void wqkv_pre_k(
    const float* __restrict__ qU, const float* __restrict__ qV,
    const float* __restrict__ kU, const float* __restrict__ kV,
    const float* __restrict__ vU, const float* __restrict__ vV,
    unsigned short* __restrict__ WT) {
  __shared__ float Us[64][48];
  __shared__ float Vs[48][64];
  const int m = blockIdx.y >> 4, h = blockIdx.y & 15;
  const int d0 = blockIdx.x * 64;
  const float* U = (m == 0) ? qU : (m == 1 ? kU : vU);
  const float* V = (m == 0) ? qV : (m == 1 ? kV : vV);
  const float qs = (m == 0) ? QSCALE : 1.0f;
  const int t = threadIdx.x;
  for (int idx = t; idx < 64 * 48; idx += 256) {
    const int d = idx / 48, r = idx - d * 48;
    Us[d][r] = U[(size_t)(d0 + d) * 768 + h * 48 + r];
  }
  for (int idx = t; idx < 48 * 64; idx += 256) {
    const int r = idx >> 6, e = idx & 63;
    Vs[r][e] = V[(h * 48 + r) * 64 + e];
  }
  __syncthreads();
  const int e = t & 63, dg = t >> 6;
  for (int j = 0; j < 16; ++j) {
    const int d = dg * 16 + j;
    float s = 0.f;
#pragma unroll
    for (int r = 0; r < 48; ++r) s = fmaf(Us[d][r], Vs[r][e], s);
    WT[(size_t)(m * 1024 + h * 64 + e) * 1024 + d0 + d] = f2bf(s * qs);
  }
}

// LayerNorm over D=1024, fp32 in, bf16 out. One block per row.
__global__ __launch_bounds__(256) void ln_k(
    const float* __restrict__ in, const float* __restrict__ gw,
    const float* __restrict__ bw, unsigned short* __restrict__ out) {
  const int row = blockIdx.x, t = threadIdx.x;
  const f32x4 v = *(const f32x4*)(in + (size_t)row * 1024 + t * 4);
  float s = v[0] + v[1] + v[2] + v[3];
  float ss = v[0] * v[0] + v[1] * v[1] + v[2] * v[2] + v[3] * v[3];
#pragma unroll
  for (int off = 1; off < 64; off <<= 1) {
    s += __shfl_xor(s, off);
    ss += __shfl_xor(ss, off);
  }
  __shared__ float red[8];
  if ((t & 63) == 0) { red[(t >> 6) * 2] = s; red[(t >> 6) * 2 + 1] = ss; }
  __syncthreads();
  s = red[0] + red[2] + red[4] + red[6];
  ss = red[1] + red[3] + red[5] + red[7];
  const float mean = s * (1.0f / 1024.0f);
  const float rstd = rsqrtf(ss * (1.0f / 1024.0f) - mean * mean + 1e-5f);
  const f32x4 g4 = *(const f32x4*)(gw + t * 4);
  const f32x4 b4 = *(const f32x4*)(bw + t * 4);
  u16x4 o;
#pragma unroll
  for (int i = 0; i < 4; ++i) o[i] = f2bf((v[i] - mean) * rstd * g4[i] + b4[i]);
  *(u16x4*)(out + (size_t)row * 1024 + t * 4) = o;
}

// bijective XCD chunking (m157/m204)
__device__ __forceinline__ void xcd_swz(int& bx, int& by, int nx, int ny) {
  const int nwg = nx * ny;
  if ((nwg & 7) == 0) {
    const int d = by * nx + bx;
    const int k = (d & 7) * (nwg >> 3) + (d >> 3);
    bx = k % nx;
    by = k / nx;
  }
}

// ---------------- generic bf16 MFMA GEMM ----------------
// 4-buffer global_load_lds pipeline, counted vmcnt + raw s_barrier (T3/T4),
// K-loop UNROLLED BY 4 so every buffer index / LDS offset is a compile-time
// literal (kills the VALU address-recompute bloat that capped R10/R11 at
// ~11% MfmaUtil). Requires nk = K/32 to be a multiple of 4 and >= 8 (true
// for all shapes here). bf16 out via per-wave LDS bounce (coalesced b128).
template <int BM, int BN, int EPI, int OUTBF>
__global__ __launch_bounds__(256) void gemm_k(
    const unsigned short* __restrict__ A, const unsigned short* __restrict__ Bt,
    const float* __restrict__ bias, const float* __restrict__ resid,
    void* __restrict__ Cout, int M, int N, int K) {
  constexpr int MI = BM / 32;
  constexpr int FN = BN / 32;
  constexpr int NL = (BM == 128 ? 2 : 1) + (BN == 128 ? 2 : 1);  // gloads/stage
  constexpr int ASZ = BM * 32, BSZ = BN * 32;
  constexpr int SM_KLOOP = 4 * (ASZ + BSZ);
  constexpr int SM_EPI = OUTBF ? 4 * (BM / 2) * 72 : 0;
  constexpr int SME = SM_KLOOP > SM_EPI ? SM_KLOOP : SM_EPI;
  __shared__ unsigned short smem[SME];
  unsigned short* As = smem;                  // [4][ASZ]
  unsigned short* Bs = smem + 4 * ASZ;        // [4][BSZ]
  int bxi = blockIdx.x, byi = blockIdx.y;
  xcd_swz(bxi, byi, gridDim.x, gridDim.y);
  const int t = threadIdx.x;
  const int lane = t & 63, wid = t >> 6;
  const int m0 = byi * BM, n0 = bxi * BN;
  const int wm = (wid >> 1) * (BM / 2), wn = (wid & 1) * (BN / 2);
  const int fr = lane & 15, fg = (lane >> 4) * 8;

  f32x4 acc[MI][FN];
#pragma unroll
  for (int i = 0; i < MI; ++i)
#pragma unroll
    for (int j = 0; j < FN; ++j) acc[i][j] = (f32x4){0.f, 0.f, 0.f, 0.f};

  // staging streams: advance by 32 elems per stage (single add per stream)
  const unsigned short* a0 = A + (size_t)(m0 + (t >> 2)) * K + (t & 3) * 8;
  const unsigned short* a1 = a0 + (size_t)64 * K;
  const unsigned short* b0 = Bt + (size_t)(n0 + (t >> 2)) * K + (t & 3) * 8;
  const unsigned short* b1 = b0 + (size_t)64 * K;
  const int l0 = t * 8;
  // invariant ds_read bases (all other offsets are compile-time literals)
  const int aBase = (wm + fr) * 32 + fg;
  const int bBase = (wn + fr) * 32 + fg;

#define STAGE(BUF)                                            \
  {                                                           \
    gload16(a0, &As[(BUF) * ASZ + l0]);                       \
    if (BM == 128) gload16(a1, &As[(BUF) * ASZ + l0 + 2048]); \
    gload16(b0, &Bs[(BUF) * BSZ + l0]);                       \
    if (BN == 128) gload16(b1, &Bs[(BUF) * BSZ + l0 + 2048]); \
    a0 += 32;                                                 \
    if (BM == 128) a1 += 32;                                  \
    b0 += 32;                                                 \
    if (BN == 128) b1 += 32;                                  \
  }
#define COMPUTE(P)                                                          \
  {                                                                         \
    bf16x8 af[MI], bfr[FN];                                                 \
    _Pragma("unroll") for (int i = 0; i < MI; ++i)                          \
        af[i] = *(const bf16x8*)&As[(P) * ASZ + aBase + i * 512];           \
    _Pragma("unroll") for (int j = 0; j < FN; ++j)                          \
        bfr[j] = *(const bf16x8*)&Bs[(P) * BSZ + bBase + j * 512];          \
    _Pragma("unroll") for (int i = 0; i < MI; ++i)                          \
        _Pragma("unroll") for (int j = 0; j < FN; ++j)                      \
            acc[i][j] = mfma16(af[i], bfr[j], acc[i][j]);                   \
  }
#define W2 asm volatile("s_waitcnt vmcnt(%0)" ::"n"(2 * NL) : "memory")
#define W1 asm volatile("s_waitcnt vmcnt(%0)" ::"n"(NL) : "memory")
#define W0 asm volatile("s_waitcnt vmcnt(0)" ::: "memory")
#define BARR                                                  \
  __builtin_amdgcn_s_barrier();                               \
  __builtin_amdgcn_sched_barrier(0)

  const int nk = K >> 5;  // multiple of 4, >= 8 for all shapes used
  STAGE(0) STAGE(1) STAGE(2)

  for (int base = 0; base + 8 <= nk; base += 4) {
    W2; BARR; STAGE(3) COMPUTE(0)
    W2; BARR; STAGE(0) COMPUTE(1)
    W2; BARR; STAGE(1) COMPUTE(2)
    W2; BARR; STAGE(2) COMPUTE(3)
  }
  // tail mega-iter (tiles nk-4..nk-1): one last stage, then drain ladder
  W2; BARR; STAGE(3) COMPUTE(0)
  W2; BARR; COMPUTE(1)
  W1; BARR; COMPUTE(2)
  W0; BARR; COMPUTE(3)

#undef STAGE
#undef COMPUTE
#undef W2
#undef W1
#undef W0
#undef BARR

  if (OUTBF) {
    __syncthreads();  // all waves out of the K-loop before smem reuse
    unsigned short* eb = smem + wid * ((BM / 2) * 72);  // per-wave [BM/2][72] bf16
#pragma unroll
    for (int j = 0; j < FN; ++j) {
      const int colL = j * 16 + fr;                     // wave-local column
      const float bval = (EPI >= 1) ? bias[n0 + wn + colL] : 0.0f;
#pragma unroll
      for (int i = 0; i < MI; ++i) {
#pragma unroll
        for (int r = 0; r < 4; ++r) {
          const int rl = i * 16 + ((lane >> 4) << 2) + r;
          float v = acc[i][j][r] + bval;
          if (EPI == 2) {  // gelu tanh-approx: v * sigmoid(2z)
            const float z = 0.7978845608028654f * (v + 0.044715f * v * v * v);
            v = v - v / (__expf(2.0f * z) + 1.0f);
          }
          eb[rl * 72 + colL] = f2bf(v);
        }
      }
    }
    __builtin_amdgcn_s_barrier();
    constexpr int CH = (BN / 2) / 8;
    constexpr int RPI = 64 / CH;             // rows per pass
    const int c2 = lane % CH, r2b = lane / CH;
    unsigned short* Cg = (unsigned short*)Cout;
#pragma unroll
    for (int it = 0; it < (BM / 2) / RPI; ++it) {
      const int r2 = r2b + it * RPI;
      const u16x8 vv = *(const u16x8*)&eb[r2 * 72 + c2 * 8];
      *(u16x8*)&Cg[(size_t)(m0 + wm + r2) * N + n0 + wn + c2 * 8] = vv;
    }
  } else {
#pragma unroll
    for (int j = 0; j < FN; ++j) {
      const int col = n0 + wn + j * 16 + fr;
      const float bval = (EPI >= 1) ? bias[col] : 0.0f;
#pragma unroll
      for (int i = 0; i < MI; ++i) {
#pragma unroll
        for (int r = 0; r < 4; ++r) {
          const int row = m0 + wm + i * 16 + ((lane >> 4) << 2) + r;
          float v = acc[i][j][r] + bval;
          if (EPI == 3) v += resid[(size_t)row * N + col];
          ((float*)Cout)[(size_t)row * N + col] = v;
        }
      }
    }
  }
}

// ---------------- causal flash attention (R10 structure + T13 defer-max) ----------------
__global__ __launch_bounds__(512) void attn_k(
    const unsigned short* __restrict__ QKV, const unsigned short* __restrict__ VT,
    unsigned short* __restrict__ ctx) {
  __shared__ unsigned short Ks[2][64 * 64];
  __shared__ unsigned short Vs[2][64 * 64];
  __shared__ unsigned short Ps[8][16 * 64];  // per-wave P, 16B-chunk swizzled by q&7
  int bxi = blockIdx.x, byi = blockIdx.y;
  xcd_swz(bxi, byi, 16, 32);
  const int qi = ((byi >> 1) & 1) ? (15 - bxi) : bxi;
  const int bh = byi, b = bh >> 4, h = bh & 15;
  const int nt = 2 * qi + 2;
  const int q0b = qi * 128;
  const int t = threadIdx.x, lane = t & 63, w = t >> 6;
  const int g = lane >> 4, c = lane & 15;
  const int cks = c & 7;
  const size_t base = (size_t)b * 2048 * 3072;

  const int r0 = t >> 3, ch0 = t & 7;
  const int lw = r0 * 64 + ((ch0 ^ (r0 & 7)) * 8);
  const unsigned short* Kg = QKV + base + 1024 + h * 64 + (size_t)r0 * 3072 + ch0 * 8;
  const unsigned short* Vg = VT + ((size_t)bh * 64 + r0) * 2048 + ch0 * 8;

  const int kro0 = (g ^ cks) * 8, kro1 = ((4 + g) ^ cks) * 8;

  bf16x8 onef;
#pragma unroll
  for (int i = 0; i < 8; ++i) onef[i] = (__bf16)1.0f;

  const int qrow = q0b + w * 16 + c;
  const unsigned short* qp = QKV + base + (size_t)qrow * 3072 + h * 64 + g * 8;
  const bf16x8 qf0 = *(const bf16x8*)qp;
  const bf16x8 qf1 = *(const bf16x8*)(qp + 32);

  f32x4 o[4];
#pragma unroll
  for (int d = 0; d < 4; ++d) o[d] = (f32x4){0.f, 0.f, 0.f, 0.f};
  f32x4 ol = (f32x4){0.f, 0.f, 0.f, 0.f};
  float mrow = -1e30f;

  u16x8 kr, vr;
#define ATTN_LOAD(kt_)                                        \
  {                                                           \
    kr = *(const u16x8*)(Kg + (size_t)(kt_) * 64 * 3072);     \
    vr = *(const u16x8*)(Vg + (kt_) * 64);                    \
  }
#define ATTN_WRITE(buf)                                       \
  {                                                           \
    *(u16x8*)&Ks[buf][lw] = kr;                               \
    *(u16x8*)&Vs[buf][lw] = vr;                               \
  }

  ATTN_LOAD(0);
  ATTN_WRITE(0);
  if (nt > 1) ATTN_LOAD(1);
  __syncthreads();

  const int fsrc = g * 20;

  for (int j = 0; j < nt; ++j) {
    const int cur = j & 1;
    const int kbase = j * 64;
    const bool active = (kbase <= q0b + w * 16 + 15);

    if (active) {
      f32x4 s4[4];
      __builtin_amdgcn_s_setprio(1);
#pragma unroll
      for (int t16 = 0; t16 < 4; ++t16) {
        const int krow = (t16 * 16 + c) * 64;
        const bf16x8 kf0 = *(const bf16x8*)&Ks[cur][krow + kro0];
        const bf16x8 kf1 = *(const bf16x8*)&Ks[cur][krow + kro1];
        f32x4 a = (f32x4){0.f, 0.f, 0.f, 0.f};
        a = mfma16(kf0, qf0, a);
        a = mfma16(kf1, qf1, a);
        s4[t16] = a;
      }
      __builtin_amdgcn_s_setprio(0);
      if (kbase + 63 > qrow) {
#pragma unroll
        for (int t16 = 0; t16 < 4; ++t16)
#pragma unroll
          for (int r = 0; r < 4; ++r)
            if (kbase + t16 * 16 + 4 * g + r > qrow) s4[t16][r] = -1e30f;
      }
      float mx = s4[0][0];
#pragma unroll
      for (int t16 = 0; t16 < 4; ++t16)
#pragma unroll
        for (int r = 0; r < 4; ++r) mx = fmaxf(mx, s4[t16][r]);
      mx = fmaxf(mx, __shfl_xor(mx, 16));
      mx = fmaxf(mx, __shfl_xor(mx, 32));
      // T13 defer-max: rescale only when the running max grew by > 8
      if (!__all(mx <= mrow + 8.0f)) {
        const float mn = fmaxf(mrow, mx);
        const float fac = exp2f(mrow - mn);
        mrow = mn;
        float fo[4];
#pragma unroll
        for (int r = 0; r < 4; ++r) fo[r] = __shfl(fac, fsrc + r);
#pragma unroll
        for (int d = 0; d < 4; ++d)
#pragma unroll
          for (int r = 0; r < 4; ++r) o[d][r] *= fo[r];
#pragma unroll
        for (int r = 0; r < 4; ++r) ol[r] *= fo[r];
      }
#pragma unroll
      for (int t16 = 0; t16 < 4; ++t16) {
        bf16x4 pw;
#pragma unroll
        for (int r = 0; r < 4; ++r) pw[r] = (__bf16)exp2f(s4[t16][r] - mrow);
        *(bf16x4*)&Ps[w][c * 64 + (((2 * t16 + (g >> 1)) ^ cks) * 8) + (g & 1) * 4] = pw;
      }
      __builtin_amdgcn_s_setprio(1);
#pragma unroll
      for (int ks = 0; ks < 2; ++ks) {
        const int po = ((ks * 4 + g) ^ cks) * 8;
        const bf16x8 pf = *(const bf16x8*)&Ps[w][c * 64 + po];
#pragma unroll
        for (int d = 0; d < 4; ++d) {
          const bf16x8 vf = *(const bf16x8*)&Vs[cur][(d * 16 + c) * 64 + po];
          o[d] = mfma16(pf, vf, o[d]);
        }
        ol = mfma16(pf, onef, ol);
      }
      __builtin_amdgcn_s_setprio(0);
    }

    if (j + 1 < nt) {
      __syncthreads();
      ATTN_WRITE(cur ^ 1);
      if (j + 2 < nt) ATTN_LOAD(j + 2);
      __syncthreads();
    }
  }
#pragma unroll
  for (int d = 0; d < 4; ++d)
#pragma unroll
    for (int r = 0; r < 4; ++r) {
      const float v = o[d][r] / ol[r];
      ctx[(size_t)(b * 2048 + q0b + w * 16 + g * 4 + r) * 1024 + h * 64 + d * 16 + c] = f2bf(v);
    }
#undef ATTN_LOAD
#undef ATTN_WRITE
}

// ---------------- launch ----------------

extern "C" void kernel_launch(void* const* d_in, const int* in_sizes, int n_in,
                              void* d_out, int out_size, void* d_ws, size_t ws_size,
                              hipStream_t stream) {
  const float* hidden = (const float*)d_in[0];
  const float* ln1g = (const float*)d_in[1];
  const float* ln1b = (const float*)d_in[2];
  const float* ln2g = (const float*)d_in[3];
  const float* ln2b = (const float*)d_in[4];
  const float* qU = (const float*)d_in[5];
  const float* qV = (const float*)d_in[6];
  const float* qb = (const float*)d_in[7];
  const float* kU = (const float*)d_in[8];
  const float* kV = (const float*)d_in[9];
  const float* kb = (const float*)d_in[10];
  const float* vU = (const float*)d_in[11];
  const float* vV = (const float*)d_in[12];
  const float* vb = (const float*)d_in[13];
  const float* outU = (const float*)d_in[14];
  const float* outV = (const float*)d_in[15];
  const float* outb = (const float*)d_in[16];
  const float* fc1U = (const float*)d_in[17];
  const float* fc1V = (const float*)d_in[18];
  const float* fc1b = (const float*)d_in[19];
  const float* fc2U = (const float*)d_in[20];
  const float* fc2V = (const float*)d_in[21];
  const float* fc2b = (const float*)d_in[22];
  float* out = (float*)d_out;

  // workspace carve, lifetime-based aliasing
  char* p = (char*)d_ws;
  unsigned short* x1x2 = (unsigned short*)p; p += (size_t)4096 * 1024 * 2;   // x1 (LN1), later x2 (LN2)
  unsigned short* WqT_t1 = (unsigned short*)p; p += (size_t)3072 * 1024 * 2; // Wqkv^T, later t1
  float* bqkv = (float*)p; p += 3072 * 4;
  char* bigA = p; p += (size_t)4096 * 3072 * 2 + (size_t)4096 * 1024 * 2;    // QKV + ctx, later hmid
  unsigned short* QKV = (unsigned short*)bigA;
  unsigned short* ctxb = (unsigned short*)(bigA + (size_t)4096 * 3072 * 2);
  unsigned short* hmid = (unsigned short*)bigA;
  char* wo = p; p += (size_t)1024 * 768 * 2 * 2 + (size_t)1024 * 1024 * 2;   // outU,outV^T,Wout^T, later t2
  unsigned short* outUb = (unsigned short*)wo;
  unsigned short* outVT = (unsigned short*)(wo + (size_t)1024 * 768 * 2);
  unsigned short* WoutT = (unsigned short*)(wo + (size_t)1024 * 768 * 2 * 2);
  unsigned short* t2 = (unsigned short*)wo;
  float* hbuf = (float*)p; p += (size_t)4096 * 1024 * 4;                     // h (fp32 residual); VT aliases pre-attn
  unsigned short* VT = (unsigned short*)hbuf;                                // [32][64][2048] bf16 = 8MB
  unsigned short* fc1UT = (unsigned short*)p; p += (size_t)512 * 1024 * 2;
  unsigned short* fc1VT = (unsigned short*)p; p += (size_t)4096 * 512 * 2;
  unsigned short* fc2UT = (unsigned short*)p; p += (size_t)512 * 4096 * 2;
  unsigned short* fc2VT = (unsigned short*)p; p += (size_t)1024 * 512 * 2;

  const dim3 b256(256);
  const dim3 tb(32, 8);

  // weight prep
  concat_bias_k<<<12, b256, 0, stream>>>(qb, kb, vb, bqkv);
  wqkv_pre_k<<<dim3(16, 48), b256, 0, stream>>>(qU, qV, kU, kV, vU, vV, WqT_t1);
  tcvt_k<<<dim3(32, 24), tb, 0, stream>>>(outV, outVT, 768, 1024);
  cvt_k<<<768, b256, 0, stream>>>(outU, outUb, 1024 * 768);
  tcvt_k<<<dim3(16, 32), tb, 0, stream>>>(fc1U, fc1UT, 1024, 512);
  tcvt_k<<<dim3(128, 16), tb, 0, stream>>>(fc1V, fc1VT, 512, 4096);
  tcvt_k<<<dim3(16, 128), tb, 0, stream>>>(fc2U, fc2UT, 4096, 512);
  tcvt_k<<<dim3(32, 16), tb, 0, stream>>>(fc2V, fc2VT, 512, 1024);

  // attention path
  ln_k<<<4096, b256, 0, stream>>>(hidden, ln1g, ln1b, x1x2);
  gemm_k<128, 128, 1, 1><<<dim3(24, 32), b256, 0, stream>>>(x1x2, WqT_t1, bqkv, nullptr, QKV, 4096, 3072, 1024);
  vtr_k<<<dim3(64, 2, 32), tb, 0, stream>>>(QKV, VT);
  gemm_k<128, 128, 0, 1><<<dim3(8, 8), b256, 0, stream>>>(outVT, outUb, nullptr, nullptr, WoutT, 1024, 1024, 768);
  attn_k<<<dim3(16, 32), dim3(512), 0, stream>>>(QKV, VT, ctxb);
  gemm_k<64, 128, 3, 0><<<dim3(8, 64), b256, 0, stream>>>(ctxb, WoutT, outb, hidden, hbuf, 4096, 1024, 1024);

  // MLP path
  ln_k<<<4096, b256, 0, stream>>>(hbuf, ln2g, ln2b, x1x2);
  gemm_k<64, 64, 0, 1><<<dim3(8, 64), b256, 0, stream>>>(x1x2, fc1UT, nullptr, nullptr, WqT_t1, 4096, 512, 1024);
  gemm_k<128, 128, 2, 1><<<dim3(32, 32), b256, 0, stream>>>(WqT_t1, fc1VT, fc1b, nullptr, hmid, 4096, 4096, 512);
  gemm_k<64, 64, 0, 1><<<dim3(8, 64), b256, 0, stream>>>(hmid, fc2UT, nullptr, nullptr, t2, 4096, 512, 4096);
  gemm_k<64, 128, 3, 0><<<dim3(8, 64), b256, 0, stream>>>(t2, fc2VT, fc2b, hbuf, out, 4096, 1024, 512);
}

// Round 13
// 259.076 us; speedup vs baseline: 1.0295x; 1.0039x over previous
//
#include <hip/hip_runtime.h>
#include <hip/hip_bf16.h>

typedef float f32x4 __attribute__((ext_vector_type(4)));
typedef __bf16 bf16x8 __attribute__((ext_vector_type(8)));
typedef __bf16 bf16x4 __attribute__((ext_vector_type(4)));
typedef unsigned short u16x8 __attribute__((ext_vector_type(8)));
typedef unsigned short u16x4 __attribute__((ext_vector_type(4)));

#define QSCALE 0.180336881f  /* 0.125 * log2(e): folds attn scale + exp2 domain into Q */

__device__ __forceinline__ unsigned short f2bf(float f) {
  union { float f; unsigned int u; } v; v.f = f;
  return (unsigned short)((v.u + 0x7FFFu + ((v.u >> 16) & 1u)) >> 16);
}

__device__ __forceinline__ f32x4 mfma16(bf16x8 a, bf16x8 b, f32x4 c) {
  return __builtin_amdgcn_mfma_f32_16x16x32_bf16(a, b, c, 0, 0, 0);
}

__device__ __forceinline__ void gload16(const unsigned short* g, unsigned short* l) {
  __builtin_amdgcn_global_load_lds(
      (const __attribute__((address_space(1))) void*)g,
      (__attribute__((address_space(3))) void*)l, 16, 0, 0);
}

// ---------------- small utility kernels ----------------

__global__ void concat_bias_k(const float* __restrict__ qb, const float* __restrict__ kb,
                              const float* __restrict__ vb, float* __restrict__ out) {
  const int i = blockIdx.x * 256 + threadIdx.x;
  if (i >= 3072) return;
  const float* s = (i < 1024) ? qb : (i < 2048 ? kb : vb);
  out[i] = s[i & 1023] * (i < 1024 ? QSCALE : 1.0f);
}

// fp32 [R,C] -> bf16 [C,R]
__global__ void tcvt_k(const float* __restrict__ in, unsigned short* __restrict__ out,
                       int R, int C) {
  __shared__ float tile[32][33];
  const int x = blockIdx.x * 32 + threadIdx.x;
  const int y0 = blockIdx.y * 32;
#pragma unroll
  for (int i = 0; i < 32; i += 8)
    tile[threadIdx.y + i][threadIdx.x] = in[(size_t)(y0 + threadIdx.y + i) * C + x];
  __syncthreads();
  const int ox = y0 + threadIdx.x;
  const int oy0 = blockIdx.x * 32;
#pragma unroll
  for (int i = 0; i < 32; i += 8)
    out[(size_t)(oy0 + threadIdx.y + i) * R + ox] = f2bf(tile[threadIdx.x][threadIdx.y + i]);
}

__global__ void cvt_k(const float* __restrict__ in, unsigned short* __restrict__ out, int n) {
  const int i = (blockIdx.x * 256 + threadIdx.x) * 4;
  if (i >= n) return;
  const f32x4 v = *(const f32x4*)(in + i);
  u16x4 o;
#pragma unroll
  for (int k = 0; k < 4; ++k) o[k] = f2bf(v[k]);
  *(u16x4*)(out + i) = o;
}

// V-transpose: QKV[b][s][2048 + h*64 + d] -> VT[(b*16+h)][d][s]  (bf16)
__global__ void vtr_k(const unsigned short* __restrict__ QKV, unsigned short* __restrict__ VT) {
  __shared__ unsigned short tile[32][33];
  const int bh = blockIdx.z, b = bh >> 4, h = bh & 15;
  const int s0 = blockIdx.x * 32, d0 = blockIdx.y * 32;
  const unsigned short* src = QKV + (size_t)b * 2048 * 3072 + 2048 + h * 64;
#pragma unroll
  for (int i = 0; i < 32; i += 8)
    tile[threadIdx.y + i][threadIdx.x] = src[(size_t)(s0 + threadIdx.y + i) * 3072 + d0 + threadIdx.x];
  __syncthreads();
  unsigned short* dst = VT + (size_t)bh * 64 * 2048;
#pragma unroll
  for (int i = 0; i < 32; i += 8)
    dst[(size_t)(d0 + threadIdx.y + i) * 2048 + s0 + threadIdx.x] = tile[threadIdx.x][threadIdx.y + i];
}

// Wqkv^T[(m*1024 + h*64 + e)*1024 + d] = sum_r U_m[d,h,r] * V_m[h,r,e]  (Q part scaled)
__global__ __launch_bounds__(256) void wqkv_pre_k(
    const float* __restrict__ qU, const float* __restrict__ qV,
    const float* __restrict__ kU, const float* __restrict__ kV,
    const float* __restrict__ vU, const float* __restrict__ vV,
    unsigned short* __restrict__ WT) {
  __shared__ float Us[64][48];
  __shared__ float Vs[48][64];
  const int m = blockIdx.y >> 4, h = blockIdx.y & 15;
  const int d0 = blockIdx.x * 64;
  const float* U = (m == 0) ? qU : (m == 1 ? kU : vU);
  const float* V = (m == 0) ? qV : (m == 1 ? kV : vV);
  const float qs = (m == 0) ? QSCALE : 1.0f;
  const int t = threadIdx.x;
  for (int idx = t; idx < 64 * 48; idx += 256) {
    const int d = idx / 48, r = idx - d * 48;
    Us[d][r] = U[(size_t)(d0 + d) * 768 + h * 48 + r];
  }
  for (int idx = t; idx < 48 * 64; idx += 256) {
    const int r = idx >> 6, e = idx & 63;
    Vs[r][e] = V[(h * 48 + r) * 64 + e];
  }
  __syncthreads();
  const int e = t & 63, dg = t >> 6;
  for (int j = 0; j < 16; ++j) {
    const int d = dg * 16 + j;
    float s = 0.f;
#pragma unroll
    for (int r = 0; r < 48; ++r) s = fmaf(Us[d][r], Vs[r][e], s);
    WT[(size_t)(m * 1024 + h * 64 + e) * 1024 + d0 + d] = f2bf(s * qs);
  }
}

// LayerNorm over D=1024, fp32 in, bf16 out. One block per row.
__global__ __launch_bounds__(256) void ln_k(
    const float* __restrict__ in, const float* __restrict__ gw,
    const float* __restrict__ bw, unsigned short* __restrict__ out) {
  const int row = blockIdx.x, t = threadIdx.x;
  const f32x4 v = *(const f32x4*)(in + (size_t)row * 1024 + t * 4);
  float s = v[0] + v[1] + v[2] + v[3];
  float ss = v[0] * v[0] + v[1] * v[1] + v[2] * v[2] + v[3] * v[3];
#pragma unroll
  for (int off = 1; off < 64; off <<= 1) {
    s += __shfl_xor(s, off);
    ss += __shfl_xor(ss, off);
  }
  __shared__ float red[8];
  if ((t & 63) == 0) { red[(t >> 6) * 2] = s; red[(t >> 6) * 2 + 1] = ss; }
  __syncthreads();
  s = red[0] + red[2] + red[4] + red[6];
  ss = red[1] + red[3] + red[5] + red[7];
  const float mean = s * (1.0f / 1024.0f);
  const float rstd = rsqrtf(ss * (1.0f / 1024.0f) - mean * mean + 1e-5f);
  const f32x4 g4 = *(const f32x4*)(gw + t * 4);
  const f32x4 b4 = *(const f32x4*)(bw + t * 4);
  u16x4 o;
#pragma unroll
  for (int i = 0; i < 4; ++i) o[i] = f2bf((v[i] - mean) * rstd * g4[i] + b4[i]);
  *(u16x4*)(out + (size_t)row * 1024 + t * 4) = o;
}

// bijective XCD chunking (m157/m204)
__device__ __forceinline__ void xcd_swz(int& bx, int& by, int nx, int ny) {
  const int nwg = nx * ny;
  if ((nwg & 7) == 0) {
    const int d = by * nx + bx;
    const int k = (d & 7) * (nwg >> 3) + (d >> 3);
    bx = k % nx;
    by = k / nx;
  }
}

#define WVM(N) asm volatile("s_waitcnt vmcnt(%0)" ::"n"(N) : "memory")

// ---------------- 256x256 8-wave phase-interleaved GEMM ----------------
// C[M,N] = A[M,K] @ Bt[N,K]^T, bf16 out. BK=32, 3 LDS buffers (96 KB, 1
// block/CU), 8 waves (2x4), wave tile 128x64, 32 MFMA per wave per barrier.
// Per K-tile: ONE vmcnt(4)+barrier (counted, never drains mid-loop; tile kt
// staged during kt-2's phases -> ~2 K-tiles of latency cover), then 4 phases
// each {ds_read quadrant frags | issue 1 stage gload | setprio'd 8 MFMA}.
// EPI: 1=+bias, 2=+bias+gelu.
template <int EPI>
__global__ __launch_bounds__(512) void gemm256_k(
    const unsigned short* __restrict__ A, const unsigned short* __restrict__ Bt,
    const float* __restrict__ bias, unsigned short* __restrict__ Cout,
    int M, int N, int K) {
  __shared__ unsigned short smem[49152];  // A[3][2][128*32] + B[3][2][128*32]
  unsigned short* Asm = smem;
  unsigned short* Bsm = smem + 24576;
  int bxi = blockIdx.x, byi = blockIdx.y;
  xcd_swz(bxi, byi, gridDim.x, gridDim.y);
  const int t = threadIdx.x;
  const int lane = t & 63, wid = t >> 6;
  const int wr = wid >> 2, wc = wid & 3;
  const int m0 = byi * 256, n0 = bxi * 256;
  const int fr = lane & 15, g = lane >> 4;

  f32x4 acc[8][4];
#pragma unroll
  for (int i = 0; i < 8; ++i)
#pragma unroll
    for (int j = 0; j < 4; ++j) acc[i][j] = (f32x4){0.f, 0.f, 0.f, 0.f};

  // staging: one 128x32 part per gload-round; thread t -> row t>>2, chunk t&3
  const unsigned short* Ag0 = A + (size_t)(m0 + (t >> 2)) * K + (t & 3) * 8;
  const unsigned short* Ag1 = A + (size_t)(m0 + 128 + (t >> 2)) * K + (t & 3) * 8;
  const unsigned short* Bg0 = Bt + (size_t)(n0 + (t >> 2)) * K + (t & 3) * 8;
  const unsigned short* Bg1 = Bt + (size_t)(n0 + 128 + (t >> 2)) * K + (t & 3) * 8;
  const int l8 = t * 8;

#define SA0(BUF, KT) gload16(Ag0 + (KT) * 32, &Asm[(BUF) * 8192 + l8]);
#define SA1(BUF, KT) gload16(Ag1 + (KT) * 32, &Asm[(BUF) * 8192 + 4096 + l8]);
#define SB0(BUF, KT) gload16(Bg0 + (KT) * 32, &Bsm[(BUF) * 8192 + l8]);
#define SB1(BUF, KT) gload16(Bg1 + (KT) * 32, &Bsm[(BUF) * 8192 + 4096 + l8]);

  const int nk = K >> 5;  // >= 3 for all uses
  SA0(0, 0) SA1(0, 0) SB0(0, 0) SB1(0, 0)
  SA0(1, 1) SA1(1, 1) SB0(1, 1) SB1(1, 1)

  int buf = 0, nbuf = 2;
  for (int kt = 0; kt < nk; ++kt) {
    if (kt + 1 < nk) WVM(4); else WVM(0);
    __builtin_amdgcn_s_barrier();
    const unsigned short* Aw = &Asm[buf * 8192 + wr * 4096];
    const unsigned short* Bw = &Bsm[buf * 8192 + (wc >> 1) * 4096 + (wc & 1) * 2048];
    const bool st = (kt + 2 < nk);
    const int kf = kt + 2;
    bf16x8 af[4], af2[4], bf[4];
    // phase 1: quadrant (0,0)
#pragma unroll
    for (int i = 0; i < 4; ++i) af[i] = *(const bf16x8*)&Aw[(i * 16 + fr) * 32 + g * 8];
#pragma unroll
    for (int j = 0; j < 2; ++j) bf[j] = *(const bf16x8*)&Bw[(j * 16 + fr) * 32 + g * 8];
    if (st) SA0(nbuf, kf)
    __builtin_amdgcn_s_setprio(1);
#pragma unroll
    for (int i = 0; i < 4; ++i)
#pragma unroll
      for (int j = 0; j < 2; ++j) acc[i][j] = mfma16(af[i], bf[j], acc[i][j]);
    __builtin_amdgcn_s_setprio(0);
    // phase 2: quadrant (0,1)
#pragma unroll
    for (int j = 2; j < 4; ++j) bf[j] = *(const bf16x8*)&Bw[(j * 16 + fr) * 32 + g * 8];
    if (st) SA1(nbuf, kf)
    __builtin_amdgcn_s_setprio(1);
#pragma unroll
    for (int i = 0; i < 4; ++i)
#pragma unroll
      for (int j = 2; j < 4; ++j) acc[i][j] = mfma16(af[i], bf[j], acc[i][j]);
    __builtin_amdgcn_s_setprio(0);
    // phase 3: quadrant (1,0)
#pragma unroll
    for (int i = 0; i < 4; ++i) af2[i] = *(const bf16x8*)&Aw[(64 + i * 16 + fr) * 32 + g * 8];
    if (st) SB0(nbuf, kf)
    __builtin_amdgcn_s_setprio(1);
#pragma unroll
    for (int i = 0; i < 4; ++i)
#pragma unroll
      for (int j = 0; j < 2; ++j) acc[4 + i][j] = mfma16(af2[i], bf[j], acc[4 + i][j]);
    __builtin_amdgcn_s_setprio(0);
    // phase 4: quadrant (1,1)
    if (st) SB1(nbuf, kf)
    __builtin_amdgcn_s_setprio(1);
#pragma unroll
    for (int i = 0; i < 4; ++i)
#pragma unroll
      for (int j = 2; j < 4; ++j) acc[4 + i][j] = mfma16(af2[i], bf[j], acc[4 + i][j]);
    __builtin_amdgcn_s_setprio(0);
    buf = (buf == 2) ? 0 : buf + 1;
    nbuf = (nbuf == 2) ? 0 : nbuf + 1;
  }
#undef SA0
#undef SA1
#undef SB0
#undef SB1

  // epilogue: 2-pass per-wave LDS bounce -> coalesced b128 stores
  __syncthreads();
  unsigned short* eb = smem + wid * 4608;  // per-wave [64][72]
#pragma unroll
  for (int ih = 0; ih < 2; ++ih) {
#pragma unroll
    for (int j = 0; j < 4; ++j) {
      const int colL = j * 16 + fr;
      const float bval = bias[n0 + wc * 64 + colL];
#pragma unroll
      for (int i2 = 0; i2 < 4; ++i2) {
#pragma unroll
        for (int r = 0; r < 4; ++r) {
          const int rl = i2 * 16 + g * 4 + r;
          float v = acc[ih * 4 + i2][j][r] + bval;
          if (EPI == 2) {
            const float z = 0.7978845608028654f * (v + 0.044715f * v * v * v);
            v = v - v / (__expf(2.0f * z) + 1.0f);
          }
          eb[rl * 72 + colL] = f2bf(v);
        }
      }
    }
#pragma unroll
    for (int it = 0; it < 8; ++it) {
      const int row = (lane >> 3) + it * 8;
      const int ch = lane & 7;
      const u16x8 vv = *(const u16x8*)&eb[row * 72 + ch * 8];
      *(u16x8*)&Cout[(size_t)(m0 + wr * 128 + ih * 64 + row) * N + n0 + wc * 64 + ch * 8] = vv;
    }
  }
}

// ---------------- generic bf16 MFMA GEMM (R12, narrow shapes) ----------------
template <int BM, int BN, int EPI, int OUTBF>
__global__ __launch_bounds__(256) void gemm_k(
    const unsigned short* __restrict__ A, const unsigned short* __restrict__ Bt,
    const float* __restrict__ bias, const float* __restrict__ resid,
    void* __restrict__ Cout, int M, int N, int K) {
  constexpr int MI = BM / 32;
  constexpr int FN = BN / 32;
  constexpr int NL = (BM == 128 ? 2 : 1) + (BN == 128 ? 2 : 1);
  constexpr int ASZ = BM * 32, BSZ = BN * 32;
  constexpr int SM_KLOOP = 4 * (ASZ + BSZ);
  constexpr int SM_EPI = OUTBF ? 4 * (BM / 2) * 72 : 0;
  constexpr int SME = SM_KLOOP > SM_EPI ? SM_KLOOP : SM_EPI;
  __shared__ unsigned short smem[SME];
  unsigned short* As = smem;
  unsigned short* Bs = smem + 4 * ASZ;
  int bxi = blockIdx.x, byi = blockIdx.y;
  xcd_swz(bxi, byi, gridDim.x, gridDim.y);
  const int t = threadIdx.x;
  const int lane = t & 63, wid = t >> 6;
  const int m0 = byi * BM, n0 = bxi * BN;
  const int wm = (wid >> 1) * (BM / 2), wn = (wid & 1) * (BN / 2);
  const int fr = lane & 15, fg = (lane >> 4) * 8;

  f32x4 acc[MI][FN];
#pragma unroll
  for (int i = 0; i < MI; ++i)
#pragma unroll
    for (int j = 0; j < FN; ++j) acc[i][j] = (f32x4){0.f, 0.f, 0.f, 0.f};

  const unsigned short* Ag0 = A + (size_t)(m0 + (t >> 2)) * K + (t & 3) * 8;
  const unsigned short* Ag1 = A + (size_t)(m0 + 64 + (t >> 2)) * K + (t & 3) * 8;
  const unsigned short* Bg0 = Bt + (size_t)(n0 + (t >> 2)) * K + (t & 3) * 8;
  const unsigned short* Bg1 = Bt + (size_t)(n0 + 64 + (t >> 2)) * K + (t & 3) * 8;
  const int l0 = t * 8;

#define GEMM_STAGE(buf, ke)                                               \
  {                                                                       \
    gload16(Ag0 + (ke), &As[(buf) * ASZ + l0]);                           \
    if (BM == 128) gload16(Ag1 + (ke), &As[(buf) * ASZ + l0 + 2048]);     \
    gload16(Bg0 + (ke), &Bs[(buf) * BSZ + l0]);                           \
    if (BN == 128) gload16(Bg1 + (ke), &Bs[(buf) * BSZ + l0 + 2048]);     \
  }

  const int nk = K >> 5;
  GEMM_STAGE(0, 0);
  if (nk > 1) GEMM_STAGE(1, 32);
  if (nk > 2) GEMM_STAGE(2, 64);

  for (int kt = 0; kt < nk; ++kt) {
    const int cur = kt & 3;
    if (kt + 2 < nk)
      WVM(2 * NL);
    else if (kt + 1 < nk)
      WVM(NL);
    else
      WVM(0);
    __builtin_amdgcn_s_barrier();
    __builtin_amdgcn_sched_barrier(0);
    if (kt + 3 < nk) GEMM_STAGE((kt + 3) & 3, (kt + 3) * 32);
    bf16x8 af[MI], bfr[FN];
#pragma unroll
    for (int i = 0; i < MI; ++i)
      af[i] = *(const bf16x8*)&As[cur * ASZ + (wm + i * 16 + fr) * 32 + fg];
#pragma unroll
    for (int j = 0; j < FN; ++j)
      bfr[j] = *(const bf16x8*)&Bs[cur * BSZ + (wn + j * 16 + fr) * 32 + fg];
#pragma unroll
    for (int i = 0; i < MI; ++i)
#pragma unroll
      for (int j = 0; j < FN; ++j) acc[i][j] = mfma16(af[i], bfr[j], acc[i][j]);
  }
#undef GEMM_STAGE

  if (OUTBF) {
    __syncthreads();
    unsigned short* eb = smem + wid * ((BM / 2) * 72);
#pragma unroll
    for (int j = 0; j < FN; ++j) {
      const int colL = j * 16 + fr;
      const float bval = (EPI >= 1) ? bias[n0 + wn + colL] : 0.0f;
#pragma unroll
      for (int i = 0; i < MI; ++i) {
#pragma unroll
        for (int r = 0; r < 4; ++r) {
          const int rl = i * 16 + ((lane >> 4) << 2) + r;
          float v = acc[i][j][r] + bval;
          if (EPI == 2) {
            const float z = 0.7978845608028654f * (v + 0.044715f * v * v * v);
            v = v - v / (__expf(2.0f * z) + 1.0f);
          }
          eb[rl * 72 + colL] = f2bf(v);
        }
      }
    }
    __builtin_amdgcn_s_barrier();
    constexpr int CH = (BN / 2) / 8;
    constexpr int RPI = 64 / CH;
    const int c2 = lane % CH, r2b = lane / CH;
    unsigned short* Cg = (unsigned short*)Cout;
#pragma unroll
    for (int it = 0; it < (BM / 2) / RPI; ++it) {
      const int r2 = r2b + it * RPI;
      const u16x8 vv = *(const u16x8*)&eb[r2 * 72 + c2 * 8];
      *(u16x8*)&Cg[(size_t)(m0 + wm + r2) * N + n0 + wn + c2 * 8] = vv;
    }
  } else {
#pragma unroll
    for (int j = 0; j < FN; ++j) {
      const int col = n0 + wn + j * 16 + fr;
      const float bval = (EPI >= 1) ? bias[col] : 0.0f;
#pragma unroll
      for (int i = 0; i < MI; ++i) {
#pragma unroll
        for (int r = 0; r < 4; ++r) {
          const int row = m0 + wm + i * 16 + ((lane >> 4) << 2) + r;
          float v = acc[i][j][r] + bval;
          if (EPI == 3) v += resid[(size_t)row * N + col];
          ((float*)Cout)[(size_t)row * N + col] = v;
        }
      }
    }
  }
}

// ---------------- causal flash attention (R10 structure + T13 defer-max) ----------------
__global__ __launch_bounds__(512) void attn_k(
    const unsigned short* __restrict__ QKV, const unsigned short* __restrict__ VT,
    unsigned short* __restrict__ ctx) {
  __shared__ unsigned short Ks[2][64 * 64];
  __shared__ unsigned short Vs[2][64 * 64];
  __shared__ unsigned short Ps[8][16 * 64];
  int bxi = blockIdx.x, byi = blockIdx.y;
  xcd_swz(bxi, byi, 16, 32);
  const int qi = ((byi >> 1) & 1) ? (15 - bxi) : bxi;
  const int bh = byi, b = bh >> 4, h = bh & 15;
  const int nt = 2 * qi + 2;
  const int q0b = qi * 128;
  const int t = threadIdx.x, lane = t & 63, w = t >> 6;
  const int g = lane >> 4, c = lane & 15;
  const int cks = c & 7;
  const size_t base = (size_t)b * 2048 * 3072;

  const int r0 = t >> 3, ch0 = t & 7;
  const int lw = r0 * 64 + ((ch0 ^ (r0 & 7)) * 8);
  const unsigned short* Kg = QKV + base + 1024 + h * 64 + (size_t)r0 * 3072 + ch0 * 8;
  const unsigned short* Vg = VT + ((size_t)bh * 64 + r0) * 2048 + ch0 * 8;

  const int kro0 = (g ^ cks) * 8, kro1 = ((4 + g) ^ cks) * 8;

  bf16x8 onef;
#pragma unroll
  for (int i = 0; i < 8; ++i) onef[i] = (__bf16)1.0f;

  const int qrow = q0b + w * 16 + c;
  const unsigned short* qp = QKV + base + (size_t)qrow * 3072 + h * 64 + g * 8;
  const bf16x8 qf0 = *(const bf16x8*)qp;
  const bf16x8 qf1 = *(const bf16x8*)(qp + 32);

  f32x4 o[4];
#pragma unroll
  for (int d = 0; d < 4; ++d) o[d] = (f32x4){0.f, 0.f, 0.f, 0.f};
  f32x4 ol = (f32x4){0.f, 0.f, 0.f, 0.f};
  float mrow = -1e30f;

  u16x8 kr, vr;
#define ATTN_LOAD(kt_)                                        \
  {                                                           \
    kr = *(const u16x8*)(Kg + (size_t)(kt_) * 64 * 3072);     \
    vr = *(const u16x8*)(Vg + (kt_) * 64);                    \
  }
#define ATTN_WRITE(buf)                                       \
  {                                                           \
    *(u16x8*)&Ks[buf][lw] = kr;                               \
    *(u16x8*)&Vs[buf][lw] = vr;                               \
  }

  ATTN_LOAD(0);
  ATTN_WRITE(0);
  if (nt > 1) ATTN_LOAD(1);
  __syncthreads();

  const int fsrc = g * 20;

  for (int j = 0; j < nt; ++j) {
    const int cur = j & 1;
    const int kbase = j * 64;
    const bool active = (kbase <= q0b + w * 16 + 15);

    if (active) {
      f32x4 s4[4];
      __builtin_amdgcn_s_setprio(1);
#pragma unroll
      for (int t16 = 0; t16 < 4; ++t16) {
        const int krow = (t16 * 16 + c) * 64;
        const bf16x8 kf0 = *(const bf16x8*)&Ks[cur][krow + kro0];
        const bf16x8 kf1 = *(const bf16x8*)&Ks[cur][krow + kro1];
        f32x4 a = (f32x4){0.f, 0.f, 0.f, 0.f};
        a = mfma16(kf0, qf0, a);
        a = mfma16(kf1, qf1, a);
        s4[t16] = a;
      }
      __builtin_amdgcn_s_setprio(0);
      if (kbase + 63 > qrow) {
#pragma unroll
        for (int t16 = 0; t16 < 4; ++t16)
#pragma unroll
          for (int r = 0; r < 4; ++r)
            if (kbase + t16 * 16 + 4 * g + r > qrow) s4[t16][r] = -1e30f;
      }
      float mx = s4[0][0];
#pragma unroll
      for (int t16 = 0; t16 < 4; ++t16)
#pragma unroll
        for (int r = 0; r < 4; ++r) mx = fmaxf(mx, s4[t16][r]);
      mx = fmaxf(mx, __shfl_xor(mx, 16));
      mx = fmaxf(mx, __shfl_xor(mx, 32));
      if (!__all(mx <= mrow + 8.0f)) {
        const float mn = fmaxf(mrow, mx);
        const float fac = exp2f(mrow - mn);
        mrow = mn;
        float fo[4];
#pragma unroll
        for (int r = 0; r < 4; ++r) fo[r] = __shfl(fac, fsrc + r);
#pragma unroll
        for (int d = 0; d < 4; ++d)
#pragma unroll
          for (int r = 0; r < 4; ++r) o[d][r] *= fo[r];
#pragma unroll
        for (int r = 0; r < 4; ++r) ol[r] *= fo[r];
      }
#pragma unroll
      for (int t16 = 0; t16 < 4; ++t16) {
        bf16x4 pw;
#pragma unroll
        for (int r = 0; r < 4; ++r) pw[r] = (__bf16)exp2f(s4[t16][r] - mrow);
        *(bf16x4*)&Ps[w][c * 64 + (((2 * t16 + (g >> 1)) ^ cks) * 8) + (g & 1) * 4] = pw;
      }
      __builtin_amdgcn_s_setprio(1);
#pragma unroll
      for (int ks = 0; ks < 2; ++ks) {
        const int po = ((ks * 4 + g) ^ cks) * 8;
        const bf16x8 pf = *(const bf16x8*)&Ps[w][c * 64 + po];
#pragma unroll
        for (int d = 0; d < 4; ++d) {
          const bf16x8 vf = *(const bf16x8*)&Vs[cur][(d * 16 + c) * 64 + po];
          o[d] = mfma16(pf, vf, o[d]);
        }
        ol = mfma16(pf, onef, ol);
      }
      __builtin_amdgcn_s_setprio(0);
    }

    if (j + 1 < nt) {
      __syncthreads();
      ATTN_WRITE(cur ^ 1);
      if (j + 2 < nt) ATTN_LOAD(j + 2);
      __syncthreads();
    }
  }
#pragma unroll
  for (int d = 0; d < 4; ++d)
#pragma unroll
    for (int r = 0; r < 4; ++r) {
      const float v = o[d][r] / ol[r];
      ctx[(size_t)(b * 2048 + q0b + w * 16 + g * 4 + r) * 1024 + h * 64 + d * 16 + c] = f2bf(v);
    }
#undef ATTN_LOAD
#undef ATTN_WRITE
}

// ---------------- launch ----------------

extern "C" void kernel_launch(void* const* d_in, const int* in_sizes, int n_in,
                              void* d_out, int out_size, void* d_ws, size_t ws_size,
                              hipStream_t stream) {
  const float* hidden = (const float*)d_in[0];
  const float* ln1g = (const float*)d_in[1];
  const float* ln1b = (const float*)d_in[2];
  const float* ln2g = (const float*)d_in[3];
  const float* ln2b = (const float*)d_in[4];
  const float* qU = (const float*)d_in[5];
  const float* qV = (const float*)d_in[6];
  const float* qb = (const float*)d_in[7];
  const float* kU = (const float*)d_in[8];
  const float* kV = (const float*)d_in[9];
  const float* kb = (const float*)d_in[10];
  const float* vU = (const float*)d_in[11];
  const float* vV = (const float*)d_in[12];
  const float* vb = (const float*)d_in[13];
  const float* outU = (const float*)d_in[14];
  const float* outV = (const float*)d_in[15];
  const float* outb = (const float*)d_in[16];
  const float* fc1U = (const float*)d_in[17];
  const float* fc1V = (const float*)d_in[18];
  const float* fc1b = (const float*)d_in[19];
  const float* fc2U = (const float*)d_in[20];
  const float* fc2V = (const float*)d_in[21];
  const float* fc2b = (const float*)d_in[22];
  float* out = (float*)d_out;

  // workspace carve, lifetime-based aliasing
  char* p = (char*)d_ws;
  unsigned short* x1x2 = (unsigned short*)p; p += (size_t)4096 * 1024 * 2;   // x1 (LN1), later x2 (LN2)
  unsigned short* WqT_t1 = (unsigned short*)p; p += (size_t)3072 * 1024 * 2; // Wqkv^T, later t1
  float* bqkv = (float*)p; p += 3072 * 4;
  char* bigA = p; p += (size_t)4096 * 3072 * 2 + (size_t)4096 * 1024 * 2;    // QKV + ctx, later hmid
  unsigned short* QKV = (unsigned short*)bigA;
  unsigned short* ctxb = (unsigned short*)(bigA + (size_t)4096 * 3072 * 2);
  unsigned short* hmid = (unsigned short*)bigA;
  char* wo = p; p += (size_t)1024 * 768 * 2 * 2 + (size_t)1024 * 1024 * 2;   // outU,outV^T,Wout^T, later t2
  unsigned short* outUb = (unsigned short*)wo;
  unsigned short* outVT = (unsigned short*)(wo + (size_t)1024 * 768 * 2);
  unsigned short* WoutT = (unsigned short*)(wo + (size_t)1024 * 768 * 2 * 2);
  unsigned short* t2 = (unsigned short*)wo;
  float* hbuf = (float*)p; p += (size_t)4096 * 1024 * 4;                     // h (fp32 residual); VT aliases pre-attn
  unsigned short* VT = (unsigned short*)hbuf;                                // [32][64][2048] bf16 = 8MB
  unsigned short* fc1UT = (unsigned short*)p; p += (size_t)512 * 1024 * 2;
  unsigned short* fc1VT = (unsigned short*)p; p += (size_t)4096 * 512 * 2;
  unsigned short* fc2UT = (unsigned short*)p; p += (size_t)512 * 4096 * 2;
  unsigned short* fc2VT = (unsigned short*)p; p += (size_t)1024 * 512 * 2;

  const dim3 b256(256);
  const dim3 tb(32, 8);

  // weight prep
  concat_bias_k<<<12, b256, 0, stream>>>(qb, kb, vb, bqkv);
  wqkv_pre_k<<<dim3(16, 48), b256, 0, stream>>>(qU, qV, kU, kV, vU, vV, WqT_t1);
  tcvt_k<<<dim3(32, 24), tb, 0, stream>>>(outV, outVT, 768, 1024);
  cvt_k<<<768, b256, 0, stream>>>(outU, outUb, 1024 * 768);
  tcvt_k<<<dim3(16, 32), tb, 0, stream>>>(fc1U, fc1UT, 1024, 512);
  tcvt_k<<<dim3(128, 16), tb, 0, stream>>>(fc1V, fc1VT, 512, 4096);
  tcvt_k<<<dim3(16, 128), tb, 0, stream>>>(fc2U, fc2UT, 4096, 512);
  tcvt_k<<<dim3(32, 16), tb, 0, stream>>>(fc2V, fc2VT, 512, 1024);

  // attention path
  ln_k<<<4096, b256, 0, stream>>>(hidden, ln1g, ln1b, x1x2);
  gemm256_k<1><<<dim3(12, 16), dim3(512), 0, stream>>>(x1x2, WqT_t1, bqkv, QKV, 4096, 3072, 1024);
  vtr_k<<<dim3(64, 2, 32), tb, 0, stream>>>(QKV, VT);
  gemm_k<128, 128, 0, 1><<<dim3(8, 8), b256, 0, stream>>>(outVT, outUb, nullptr, nullptr, WoutT, 1024, 1024, 768);
  attn_k<<<dim3(16, 32), dim3(512), 0, stream>>>(QKV, VT, ctxb);
  gemm_k<64, 128, 3, 0><<<dim3(8, 64), b256, 0, stream>>>(ctxb, WoutT, outb, hidden, hbuf, 4096, 1024, 1024);

  // MLP path
  ln_k<<<4096, b256, 0, stream>>>(hbuf, ln2g, ln2b, x1x2);
  gemm_k<64, 64, 0, 1><<<dim3(8, 64), b256, 0, stream>>>(x1x2, fc1UT, nullptr, nullptr, WqT_t1, 4096, 512, 1024);
  gemm256_k<2><<<dim3(16, 16), dim3(512), 0, stream>>>(WqT_t1, fc1VT, fc1b, hmid, 4096, 4096, 512);
  gemm_k<64, 64, 0, 1><<<dim3(8, 64), b256, 0, stream>>>(hmid, fc2UT, nullptr, nullptr, t2, 4096, 512, 4096);
  gemm_k<64, 128, 3, 0><<<dim3(8, 64), b256, 0, stream>>>(t2, fc2VT, fc2b, hbuf, out, 4096, 1024, 512);
}